// Round 4
// baseline (140873.376 us; speedup 1.0000x reference)
//
#include <hip/hip_runtime.h>
#include <hip/hip_cooperative_groups.h>
#include <math.h>

namespace cg = cooperative_groups;

typedef float f4 __attribute__((ext_vector_type(4)));
typedef _Float16 f16x8 __attribute__((ext_vector_type(8)));
typedef _Float16 f16x4 __attribute__((ext_vector_type(4)));

#define Hdim 2048
#define Bdim 256
#define Tdim 512
#define Odim 14
#define G3   6144   // 3*Hdim

// ---------------------------------------------------------------------------
// Prep kernels (once per launch)
// ---------------------------------------------------------------------------

__global__ void prep_gtable(const float* __restrict__ b_ih,
                            const float* __restrict__ W_ih,
                            float* __restrict__ Gt) {
    int idx = blockIdx.x * 256 + threadIdx.x;
    if (idx >= 15 * G3) return;
    int c = idx / G3, row = idx % G3;
    float v = b_ih[row];
    if (c < Odim) v += W_ih[row * Odim + c];
    Gt[idx] = v;
}

__global__ void prep_gi0(const float* __restrict__ b_ih,
                         const float* __restrict__ W_ih,
                         const float* __restrict__ target,
                         float* __restrict__ gi0) {
    int idx = blockIdx.x * 256 + threadIdx.x;
    int b = idx / G3, row = idx % G3;
    const float* x0 = target + (size_t)b * (Tdim * Odim);
    float s = b_ih[row];
    #pragma unroll
    for (int c = 0; c < Odim; ++c)
        s = fmaf(fmaxf(x0[c], 0.f), W_ih[row * Odim + c], s);
    gi0[idx] = s;
}

// W_hh (6144x2048 f32) -> hi/lo fp16 frag-major: [nt][kb][lane][8]
// n = nt*16 + (lane&15), k = kb*32 + (lane>>4)*8 + j
__global__ void prep_Bpack(const float* __restrict__ W,
                           _Float16* __restrict__ Bh, _Float16* __restrict__ Bl) {
    int idx = blockIdx.x * 256 + threadIdx.x;  // 6144*256 threads
    int n = idx >> 8, kc = idx & 255;
    const float* src = W + (size_t)n * Hdim + kc * 8;
    int kb = kc >> 2, q = kc & 3;
    int lane = (n & 15) + 16 * q;
    int nt = n >> 4;
    f16x8 vh, vl;
    #pragma unroll
    for (int j = 0; j < 8; ++j) {
        float w = src[j];
        _Float16 h = (_Float16)w;
        vh[j] = h;
        vl[j] = (_Float16)(w - (float)h);
    }
    size_t off = (((size_t)nt * 64 + kb) * 64 + lane) * 8;
    *(f16x8*)(Bh + off) = vh;
    *(f16x8*)(Bl + off) = vl;
}

// enc_hidden (256x2048 f32) -> hi/lo fp16 frag-major: [mt][kb][lane][8]
__global__ void prep_A0(const float* __restrict__ h0,
                        _Float16* __restrict__ Ah, _Float16* __restrict__ Al) {
    int idx = blockIdx.x * 256 + threadIdx.x;  // 256*256 threads
    int m = idx >> 8, kc = idx & 255;
    const float* src = h0 + (size_t)m * Hdim + kc * 8;
    int kb = kc >> 2, q = kc & 3;
    int lane = (m & 15) + 16 * q;
    int mt = m >> 4;
    f16x8 vh, vl;
    #pragma unroll
    for (int j = 0; j < 8; ++j) {
        float w = src[j];
        _Float16 h = (_Float16)w;
        vh[j] = h;
        vl[j] = (_Float16)(w - (float)h);
    }
    size_t off = (((size_t)mt * 64 + kb) * 64 + lane) * 8;
    *(f16x8*)(Ah + off) = vh;
    *(f16x8*)(Al + off) = vl;
}

// ---------------------------------------------------------------------------
// v5: ONE persistent cooperative kernel containing the whole t-loop.
// grid = 256 blocks (1/CU, coop-validated co-resident), 512 thr (8 waves).
//
// Per iteration:
//   Phase 1 (GEMM, v3 body): block (nblk = bid&63, ks = bid>>6) computes
//     C[256M x 96N] partial over its 512-K slice with hi/lo fp16 MFMA
//     (16x16x32), LDS 2x48 KB double-buffered B via global_load_lds w=16.
//   grid.sync (+ device fences for cross-XCD visibility / L1 invalidate)
//   Phase 2 (epilogue): block b=bid sums 4 K-partials + gates + writes h,
//     hi/lo A-pack, logits/argmax/log_softmax/topi.
//   grid.sync
//
// Replaces 1024 kernel launches (+ramp/drain + cold L1 each) with in-kernel
// barriers.
// ---------------------------------------------------------------------------
__global__ __launch_bounds__(512)
void step_loop(const _Float16* __restrict__ Bh, const _Float16* __restrict__ Bl,
               _Float16* __restrict__ Ah, _Float16* __restrict__ Al,
               float* __restrict__ Cpart,
               const float* __restrict__ enc_hidden,
               float* __restrict__ hb0, float* __restrict__ hb1,
               const float* __restrict__ Gt, const float* __restrict__ gi0,
               const float* __restrict__ b_hh,
               const float* __restrict__ W_out, const float* __restrict__ b_out,
               int* __restrict__ topibuf,
               float* __restrict__ lp, float* __restrict__ hfin) {
    cg::grid_group grid = cg::this_grid();

    // GEMM B double-buffer (96 KB) + epilogue scratch (separate, ~8.3 KB)
    __shared__ __align__(16) _Float16 sB[2][24576];
    __shared__ __align__(16) float sh[Hdim];
    __shared__ float sl[16];
    __shared__ int s_sel;
    __shared__ unsigned long long s_m[4];

    const int tid = threadIdx.x;
    const int bid = blockIdx.x;
    const int wave = tid >> 6, lane = tid & 63;

    // ---- GEMM decomposition (fixed per block) ----
    const int nblk = bid & 63;         // 64 N-tiles of 96
    const int ks   = bid >> 6;         // 4 K-slices of 512
    const int Mg = wave & 3;           // M-group: rows Mg*64 .. +64
    const int Ng = wave >> 2;          // N-group: frag-rows Ng*3 .. +3 (of 6)
    const int nt0 = nblk * 6;          // 6 frag-rows of 16 = 96 N
    const int kb0 = ks * 16;           // 16 kb-blocks (512 k) per slice

    // stage chunk c (4 kbl x 6 frag-rows, hi+lo = 48 KB) into sB[buf] via
    // async global->LDS. Per (i,wave) the 64 lanes cover one contiguous
    // 1 KB run -> LDS dst = wave-uniform base + lane*16 (legal).
    auto stage = [&](int buf, int c) {
        #pragma unroll
        for (int i = 0; i < 6; ++i) {
            int e = i * 512 + tid;                // 0..3071
            int half = (e >= 1536) ? 1 : 0;       // 0 = hi, 1 = lo
            int r = e - half * 1536;
            int blk = r >> 6, l = e & 63;
            int ntl = blk >> 2, kbl = blk & 3;
            const _Float16* src = (half ? Bl : Bh) +
                ((((size_t)(nt0 + ntl) * 64) + kb0 + c * 4 + kbl) * 512 + l * 8);
            __builtin_amdgcn_global_load_lds(
                (const __attribute__((address_space(1))) void*)src,
                (__attribute__((address_space(3))) void*)(&sB[buf][(size_t)e * 8]),
                16, 0, 0);
        }
    };

    // epilogue fixed indices
    const int b = bid;
    const int j0 = tid * 4;

    for (int t = 0; t < Tdim; ++t) {
        // =================== Phase 1: GEMM ===================
        {
            f4 acc[4][3];
            #pragma unroll
            for (int mf = 0; mf < 4; ++mf)
                #pragma unroll
                for (int nf = 0; nf < 3; ++nf) acc[mf][nf] = (f4)0.f;

            stage(0, 0);
            __syncthreads();   // implicit vmcnt(0) drain -> buf 0 ready

            for (int c = 0; c < 4; ++c) {
                const int buf = c & 1;
                if (c < 3) stage(buf ^ 1, c + 1);
                #pragma unroll
                for (int kbl = 0; kbl < 4; ++kbl) {
                    const int kb = kb0 + c * 4 + kbl;
                    f16x8 a_h[4], a_l[4], b_h[3], b_l[3];
                    #pragma unroll
                    for (int mf = 0; mf < 4; ++mf) {
                        size_t off = (((size_t)(Mg * 4 + mf) * 64 + kb) * 64 + lane) * 8;
                        a_h[mf] = *(const f16x8*)(Ah + off);
                        a_l[mf] = *(const f16x8*)(Al + off);
                    }
                    #pragma unroll
                    for (int nf = 0; nf < 3; ++nf) {
                        int base = (((Ng * 3 + nf) * 4 + kbl) * 64 + lane) * 8;
                        b_h[nf] = *(const f16x8*)(&sB[buf][base]);
                        b_l[nf] = *(const f16x8*)(&sB[buf][12288 + base]);
                    }
                    #pragma unroll
                    for (int mf = 0; mf < 4; ++mf)
                        #pragma unroll
                        for (int nf = 0; nf < 3; ++nf) {
                            acc[mf][nf] = __builtin_amdgcn_mfma_f32_16x16x32_f16(
                                a_h[mf], b_h[nf], acc[mf][nf], 0, 0, 0);
                            acc[mf][nf] = __builtin_amdgcn_mfma_f32_16x16x32_f16(
                                a_h[mf], b_l[nf], acc[mf][nf], 0, 0, 0);
                            acc[mf][nf] = __builtin_amdgcn_mfma_f32_16x16x32_f16(
                                a_l[mf], b_h[nf], acc[mf][nf], 0, 0, 0);
                        }
                }
                __syncthreads();
            }

            // store partials: C/D frag: col(N)=lane&15, row(M)=(lane>>4)*4+q
            const size_t cbase = (size_t)ks * Bdim * G3;
            #pragma unroll
            for (int mf = 0; mf < 4; ++mf) {
                int mrow = Mg * 64 + mf * 16 + (lane >> 4) * 4;
                #pragma unroll
                for (int nf = 0; nf < 3; ++nf) {
                    int n = (nt0 + Ng * 3 + nf) * 16 + (lane & 15);
                    #pragma unroll
                    for (int q = 0; q < 4; ++q)
                        Cpart[cbase + (size_t)(mrow + q) * G3 + n] = acc[mf][nf][q];
                }
            }
        }

        __threadfence();   // release Cpart (cross-XCD)
        grid.sync();
        __threadfence();   // acquire: invalidate L1 for Cpart/topi reads

        // =================== Phase 2: epilogue ===================
        {
            const float* hprev = (t == 0) ? enc_hidden : ((t & 1) ? hb0 : hb1);
            float* hnew = (t & 1) ? hb1 : hb0;
            const int* topi_in = topibuf + ((t + 1) & 1) * 256;
            int* topi_out = topibuf + (t & 1) * 256;

            // issue partial-sum + hprev loads first (latency under ballot)
            float gsum[3][4];
            #pragma unroll
            for (int g = 0; g < 3; ++g) {
                f4 s = *(const f4*)(b_hh + g * Hdim + j0);
                #pragma unroll
                for (int k2 = 0; k2 < 4; ++k2)
                    s += *(const f4*)(Cpart + ((size_t)k2 * Bdim + b) * G3 + g * Hdim + j0);
                #pragma unroll
                for (int c = 0; c < 4; ++c) gsum[g][c] = s[c];
            }
            f4 hp = *(const f4*)(hprev + (size_t)b * Hdim + j0);

            if (t > 0) {
                if (tid < 256) {
                    int tp = topi_in[tid];
                    unsigned long long m = __ballot(tp == (Odim - 1));
                    if ((tid & 63) == 0) s_m[tid >> 6] = m;
                }
                __syncthreads();
                if (tid == 0) {
                    int bw = b >> 6, bl = b & 63;
                    unsigned long long le =
                        s_m[bw] & ((bl == 63) ? ~0ULL : ((1ULL << (bl + 1)) - 1ULL));
                    bool dead = (le != 0ULL);
                    for (int w2 = 0; w2 < bw; ++w2) dead = dead || (s_m[w2] != 0ULL);
                    s_sel = dead ? Odim : topi_in[b];
                }
                __syncthreads();
            }
            const float* gp = (t == 0) ? (gi0 + (size_t)b * G3)
                                       : (Gt + (size_t)s_sel * G3);

            float hn[4];
            {
                f4 gr = *(const f4*)(gp + j0);
                f4 gz = *(const f4*)(gp + Hdim + j0);
                f4 gn = *(const f4*)(gp + 2 * Hdim + j0);
                #pragma unroll
                for (int c = 0; c < 4; ++c) {
                    float rr = 1.f / (1.f + expf(-(gr[c] + gsum[0][c])));
                    float zz = 1.f / (1.f + expf(-(gz[c] + gsum[1][c])));
                    float nn = tanhf(fmaf(rr, gsum[2][c], gn[c]));
                    hn[c] = (1.f - zz) * nn + zz * hp[c];
                }
            }
            f4 o0;
            #pragma unroll
            for (int c = 0; c < 4; ++c) o0[c] = hn[c];
            *(f4*)(hnew + (size_t)b * Hdim + j0) = o0;
            {   // hi/lo fp16 A-pack (16x16x32 frag: mt=b>>4, kb=j0>>5)
                f16x4 vh, vl;
                #pragma unroll
                for (int c = 0; c < 4; ++c) {
                    _Float16 hh = (_Float16)hn[c];
                    vh[c] = hh;
                    vl[c] = (_Float16)(hn[c] - (float)hh);
                }
                int kb = j0 >> 5, q = (j0 >> 3) & 3, e0 = j0 & 7;
                int lane2 = (b & 15) + 16 * q, mt = b >> 4;
                size_t off = (((size_t)mt * 64 + kb) * 64 + lane2) * 8 + e0;
                *(f16x4*)(Ah + off) = vh;
                *(f16x4*)(Al + off) = vl;
            }
            *(f4*)(sh + j0) = o0;
            __syncthreads();

            const int w = tid >> 6, l = tid & 63;
            for (int o = w; o < Odim; o += 8) {
                const float* wo = W_out + (size_t)o * Hdim;
                float s = 0.f;
                #pragma unroll
                for (int i = 0; i < 32; ++i)
                    s = fmaf(sh[l + 64 * i], wo[l + 64 * i], s);
                #pragma unroll
                for (int off = 32; off >= 1; off >>= 1)
                    s += __shfl_down(s, off);
                if (l == 0) sl[o] = s + b_out[o];
            }
            __syncthreads();
            if (tid == 0) {
                float m = sl[0]; int bi = 0;
                #pragma unroll
                for (int o = 1; o < Odim; ++o)
                    if (sl[o] > m) { m = sl[o]; bi = o; }   // strict > = first max
                float ssum = 0.f;
                #pragma unroll
                for (int o = 0; o < Odim; ++o) ssum += expf(sl[o] - m);
                topi_out[b] = bi;
                sl[14] = m + logf(ssum);
            }
            __syncthreads();
            if (tid < Odim)
                lp[(size_t)b * (Tdim * Odim) + (size_t)t * Odim + tid] = sl[tid] - sl[14];
            if (t == Tdim - 1)
                *(f4*)(hfin + (size_t)b * Hdim + j0) = o0;
        }

        __threadfence();   // release h/Ah/Al/topi (cross-XCD)
        grid.sync();
        __threadfence();   // acquire: invalidate L1 for Ah/Al/topi reads
    }
}

// ---------------------------------------------------------------------------
extern "C" void kernel_launch(void* const* d_in, const int* in_sizes, int n_in,
                              void* d_out, int out_size, void* d_ws, size_t ws_size,
                              hipStream_t stream) {
    const float* enc_hidden = (const float*)d_in[1];
    const float* target     = (const float*)d_in[2];
    const float* W_ih       = (const float*)d_in[3];
    const float* W_hh       = (const float*)d_in[4];
    const float* b_ih       = (const float*)d_in[5];
    const float* b_hh       = (const float*)d_in[6];
    const float* W_out      = (const float*)d_in[7];
    const float* b_out      = (const float*)d_in[8];

    float* out  = (float*)d_out;
    float* lp   = out;
    float* hfin = out + (size_t)Bdim * Tdim * Odim;

    float* ws    = (float*)d_ws;
    float* hb0   = ws;                        // 524288
    float* hb1   = hb0 + 524288;              // 524288
    float* Gt    = hb1 + 524288;              // 92160
    float* gi0   = Gt + 15 * G3;              // 1572864
    float* Cpart = gi0 + (size_t)Bdim * G3;   // 4*1572864 used (split-K=4)
    _Float16* Ah = (_Float16*)(Cpart + 4 * (size_t)Bdim * G3);  // 524288 halves
    _Float16* Al = Ah + (size_t)Bdim * Hdim;                    // 524288
    _Float16* Bh = Al + (size_t)Bdim * Hdim;                    // 12582912
    _Float16* Bl = Bh + (size_t)G3 * Hdim;                      // 12582912
    int* topibuf = (int*)(Bl + (size_t)G3 * Hdim);              // 512 ints

    prep_gtable<<<(15 * G3 + 255) / 256, 256, 0, stream>>>(b_ih, W_ih, Gt);
    prep_gi0<<<(Bdim * G3) / 256, 256, 0, stream>>>(b_ih, W_ih, target, gi0);
    prep_Bpack<<<(G3 * 256) / 256, 256, 0, stream>>>(W_hh, Bh, Bl);
    prep_A0<<<(Bdim * 256) / 256, 256, 0, stream>>>(enc_hidden, Ah, Al);

    void* args[] = {
        (void*)&Bh, (void*)&Bl, (void*)&Ah, (void*)&Al, (void*)&Cpart,
        (void*)&enc_hidden, (void*)&hb0, (void*)&hb1,
        (void*)&Gt, (void*)&gi0, (void*)&b_hh,
        (void*)&W_out, (void*)&b_out, (void*)&topibuf,
        (void*)&lp, (void*)&hfin
    };
    hipLaunchCooperativeKernel((void*)step_loop, dim3(256), dim3(512),
                               args, 0, stream);
}

// Round 6
// 23686.952 us; speedup vs baseline: 5.9473x; 5.9473x over previous
//
#include <hip/hip_runtime.h>
#include <math.h>

typedef float f4 __attribute__((ext_vector_type(4)));
typedef _Float16 f16x8 __attribute__((ext_vector_type(8)));

#define Hdim 2048
#define Bdim 256
#define Tdim 512
#define Odim 14
#define G3   6144   // 3*Hdim

// ---------------------------------------------------------------------------
// Prep kernels (once per launch)
// ---------------------------------------------------------------------------

__global__ void prep_gtable(const float* __restrict__ b_ih,
                            const float* __restrict__ W_ih,
                            float* __restrict__ Gt) {
    int idx = blockIdx.x * 256 + threadIdx.x;
    if (idx >= 15 * G3) return;
    int c = idx / G3, row = idx % G3;
    float v = b_ih[row];
    if (c < Odim) v += W_ih[row * Odim + c];
    Gt[idx] = v;
}

__global__ void prep_gi0(const float* __restrict__ b_ih,
                         const float* __restrict__ W_ih,
                         const float* __restrict__ target,
                         float* __restrict__ gi0) {
    int idx = blockIdx.x * 256 + threadIdx.x;
    int b = idx / G3, row = idx % G3;
    const float* x0 = target + (size_t)b * (Tdim * Odim);
    float s = b_ih[row];
    #pragma unroll
    for (int c = 0; c < Odim; ++c)
        s = fmaf(fmaxf(x0[c], 0.f), W_ih[row * Odim + c], s);
    gi0[idx] = s;
}

// W_hh (6144x2048 f32) -> hi/lo fp16 frag-major: [nt][kb][lane][8]
// n = nt*16 + (lane&15), k = kb*32 + (lane>>4)*8 + j
__global__ void prep_Bpack(const float* __restrict__ W,
                           _Float16* __restrict__ Bh, _Float16* __restrict__ Bl) {
    int idx = blockIdx.x * 256 + threadIdx.x;  // 6144*256 threads
    int n = idx >> 8, kc = idx & 255;
    const float* src = W + (size_t)n * Hdim + kc * 8;
    int kb = kc >> 2, q = kc & 3;
    int lane = (n & 15) + 16 * q;
    int nt = n >> 4;
    f16x8 vh, vl;
    #pragma unroll
    for (int j = 0; j < 8; ++j) {
        float w = src[j];
        _Float16 h = (_Float16)w;
        vh[j] = h;
        vl[j] = (_Float16)(w - (float)h);
    }
    size_t off = (((size_t)nt * 64 + kb) * 64 + lane) * 8;
    *(f16x8*)(Bh + off) = vh;
    *(f16x8*)(Bl + off) = vl;
}

// enc_hidden (256x2048 f32) -> hi/lo fp16 frag-major: [mt][kb][lane][8]
__global__ void prep_A0(const float* __restrict__ h0,
                        _Float16* __restrict__ Ah, _Float16* __restrict__ Al) {
    int idx = blockIdx.x * 256 + threadIdx.x;  // 256*256 threads
    int m = idx >> 8, kc = idx & 255;
    const float* src = h0 + (size_t)m * Hdim + kc * 8;
    int kb = kc >> 2, q = kc & 3;
    int lane = (m & 15) + 16 * q;
    int mt = m >> 4;
    f16x8 vh, vl;
    #pragma unroll
    for (int j = 0; j < 8; ++j) {
        float w = src[j];
        _Float16 h = (_Float16)w;
        vh[j] = h;
        vl[j] = (_Float16)(w - (float)h);
    }
    size_t off = (((size_t)mt * 64 + kb) * 64 + lane) * 8;
    *(f16x8*)(Ah + off) = vh;
    *(f16x8*)(Al + off) = vl;
}

// ---------------------------------------------------------------------------
// Kernel 1 (v7 = v6 + K-loop fix): fused GRU step — GEMM (full K) + gates +
// h-update + A-pack. No Cpart: block owns h-cols [nb*16,+16) x batch rows
// [mb*128,+128), reads gate rows {col, 2048+col, 4096+col} of W_hh over
// full K=2048. grid 256 = 2 Mb x 128 Nb. 512 thr = 8 waves = 4 Mg x 2 Kg
// (in-block K-split 2x1024, LDS-reduced). Wave tile 32M x 48N: mf=2,
// nf=GATE(3) — each lane holds r,z,n for the same (m,col) in-register.
// B staged 2x48KB dbuf via global_load_lds w=16 (both K-halves per chunk).
// v6 BUG (absmax 1.28): loop ran 16 chunks/kg instead of 8 — kg ranges
// overlapped (K 1024-2047 double-counted) and kb 64..95 read the next
// nt-strip's weights. Fixed: 8 chunks x 4 kbl = 32 kb = K1024 per kg.
// ---------------------------------------------------------------------------
__global__ __launch_bounds__(512, 2)
void gru_step(const _Float16* __restrict__ Aih, const _Float16* __restrict__ Ail,
              const _Float16* __restrict__ Bh, const _Float16* __restrict__ Bl,
              const float* __restrict__ hprev, float* __restrict__ hnew,
              const float* __restrict__ Gt, const float* __restrict__ gi0,
              const float* __restrict__ b_hh,
              const int* __restrict__ topi_in,
              _Float16* __restrict__ Aoh, _Float16* __restrict__ Aol,
              int t) {
    // staging: [buf][kg:2][half hi/lo:2][blk = ntl*4+kbl :12][lane:64][8]
    __shared__ __align__(16) _Float16 sB[2][24576];   // 96 KB
    __shared__ unsigned long long s_m[4];
    __shared__ int s_tp[256];

    const int tid = threadIdx.x;
    const int wave = tid >> 6, lane = tid & 63;
    const int Mg = wave & 3;           // 4 M-groups of 32 rows
    const int kg = wave >> 2;          // 2 K-groups of 1024
    const int mb = blockIdx.x & 1;     // 2 M-blocks of 128
    const int nb = blockIdx.x >> 1;    // 128 N-strips of 16 h-cols

    // ---- topi ballot (t>0): prev-step argmax -> alive/sel masks ----
    // (ordered before epilogue reads by the K-loop barriers)
    if (t > 0 && tid < 256) {
        int tp = topi_in[tid];
        s_tp[tid] = tp;
        unsigned long long mk = __ballot(tp == (Odim - 1));
        if (lane == 0) s_m[tid >> 6] = mk;
    }

    f4 acc[2][3];
    #pragma unroll
    for (int mf = 0; mf < 2; ++mf)
        #pragma unroll
        for (int nf = 0; nf < 3; ++nf) acc[mf][nf] = (f4)0.f;

    // stage chunk c: both K-halves, 3 gate-strips, 4 kbl, hi+lo = 48 KB.
    // e = i*512+tid: each 64-lane run covers one contiguous 1 KB frag-row
    // slice -> LDS dst = wave-uniform base + lane*16 (legal for gload_lds).
    auto stage = [&](int buf, int c) {
        #pragma unroll
        for (int i = 0; i < 6; ++i) {
            int e = i * 512 + tid;                 // 0..3071
            int ekg = (e >= 1536) ? 1 : 0;
            int r = e - ekg * 1536;
            int half = (r >= 768) ? 1 : 0;         // 0 = hi, 1 = lo
            int r2 = r - half * 768;
            int blk = r2 >> 6, l = e & 63;
            int ntl = blk >> 2, kbl = blk & 3;     // ntl = gate
            int kb = ekg * 32 + c * 4 + kbl;       // ekg=0: kb 0..31, ekg=1: 32..63
            size_t nt = (size_t)ntl * 128 + nb;    // gate strips: nt = g*128+nb
            const _Float16* src = (half ? Bl : Bh) + ((nt * 64 + kb) * 64 + l) * 8;
            __builtin_amdgcn_global_load_lds(
                (const __attribute__((address_space(1))) void*)src,
                (__attribute__((address_space(3))) void*)(&sB[buf][(size_t)e * 8]),
                16, 0, 0);
        }
    };

    stage(0, 0);
    __syncthreads();   // implicit vmcnt(0) drain -> buf 0 ready

    const int kbase = kg * 12288;
    for (int c = 0; c < 8; ++c) {          // 8 chunks x 4 kbl = K1024 per kg
        const int buf = c & 1;
        if (c < 7) stage(buf ^ 1, c + 1);  // overlaps this chunk's MFMAs
        #pragma unroll
        for (int kl = 0; kl < 4; ++kl) {
            const int kb = kg * 32 + c * 4 + kl;
            f16x8 a_h[2], a_l[2], b_h[3], b_l[3];
            #pragma unroll
            for (int mf = 0; mf < 2; ++mf) {
                int mt = mb * 8 + Mg * 2 + mf;
                size_t off = (((size_t)mt * 64 + kb) * 64 + lane) * 8;
                a_h[mf] = *(const f16x8*)(Aih + off);
                a_l[mf] = *(const f16x8*)(Ail + off);
            }
            #pragma unroll
            for (int nf = 0; nf < 3; ++nf) {
                int base = kbase + ((nf * 4 + kl) * 64 + lane) * 8;
                b_h[nf] = *(const f16x8*)(&sB[buf][base]);
                b_l[nf] = *(const f16x8*)(&sB[buf][6144 + base]);
            }
            #pragma unroll
            for (int mf = 0; mf < 2; ++mf)
                #pragma unroll
                for (int nf = 0; nf < 3; ++nf) {
                    acc[mf][nf] = __builtin_amdgcn_mfma_f32_16x16x32_f16(
                        a_h[mf], b_h[nf], acc[mf][nf], 0, 0, 0);
                    acc[mf][nf] = __builtin_amdgcn_mfma_f32_16x16x32_f16(
                        a_h[mf], b_l[nf], acc[mf][nf], 0, 0, 0);
                    acc[mf][nf] = __builtin_amdgcn_mfma_f32_16x16x32_f16(
                        a_l[mf], b_h[nf], acc[mf][nf], 0, 0, 0);
                }
        }
        __syncthreads();
    }

    // ---- cross-Kg reduction through LDS (reuse sB as f32 scratch) ----
    float* red = (float*)sB;   // 24 KB; all sB reads completed at last barrier
    if (kg == 1) {
        #pragma unroll
        for (int mf = 0; mf < 2; ++mf)
            #pragma unroll
            for (int nf = 0; nf < 3; ++nf)
                *(f4*)&red[(((Mg * 64 + lane) * 6) + mf * 3 + nf) * 4] = acc[mf][nf];
    }
    __syncthreads();
    if (kg == 0) {
        #pragma unroll
        for (int mf = 0; mf < 2; ++mf)
            #pragma unroll
            for (int nf = 0; nf < 3; ++nf)
                acc[mf][nf] += *(const f4*)&red[(((Mg * 64 + lane) * 6) + mf * 3 + nf) * 4];

        // ---- fused gate epilogue: lane holds r,z,n (nf=0,1,2) for 8 (m,col) ----
        const int col = nb * 16 + (lane & 15);
        const float bhr = b_hh[col];
        const float bhz = b_hh[Hdim + col];
        const float bhn = b_hh[2 * Hdim + col];
        #pragma unroll
        for (int mf = 0; mf < 2; ++mf) {
            #pragma unroll
            for (int q = 0; q < 4; ++q) {
                int m = mb * 128 + Mg * 32 + mf * 16 + ((lane >> 4) << 2) + q;
                float gr, gz, gn;
                if (t == 0) {
                    const float* g = gi0 + (size_t)m * G3;
                    gr = g[col]; gz = g[Hdim + col]; gn = g[2 * Hdim + col];
                } else {
                    int bw = m >> 6, bl = m & 63;
                    unsigned long long le =
                        s_m[bw] & ((bl == 63) ? ~0ULL : ((1ULL << (bl + 1)) - 1ULL));
                    bool dead = (le != 0ULL);
                    if (bw > 0) dead = dead || (s_m[0] != 0ULL);
                    if (bw > 1) dead = dead || (s_m[1] != 0ULL);
                    if (bw > 2) dead = dead || (s_m[2] != 0ULL);
                    int sel = dead ? Odim : s_tp[m];
                    const float* g = Gt + (size_t)sel * G3;
                    gr = g[col]; gz = g[Hdim + col]; gn = g[2 * Hdim + col];
                }
                float hp = hprev[(size_t)m * Hdim + col];
                float rr = 1.f / (1.f + expf(-(gr + (acc[mf][0][q] + bhr))));
                float zz = 1.f / (1.f + expf(-(gz + (acc[mf][1][q] + bhz))));
                float nn = tanhf(fmaf(rr, acc[mf][2][q] + bhn, gn));
                float hv = (1.f - zz) * nn + zz * hp;
                hnew[(size_t)m * Hdim + col] = hv;
                // hi/lo fp16 A-pack for next step (k-index = col)
                _Float16 hh = (_Float16)hv;
                int kb2 = col >> 5, q2 = (col >> 3) & 3, e0 = col & 7;
                int lane2 = (m & 15) + 16 * q2, mt2 = m >> 4;
                size_t aoff = (((size_t)mt2 * 64 + kb2) * 64 + lane2) * 8 + e0;
                Aoh[aoff] = hh;
                Aol[aoff] = (_Float16)(hv - (float)hh);
            }
        }
    }
}

// ---------------------------------------------------------------------------
// Kernel 2: light logits epilogue. grid 256 (wg = batch row b), 512 thr.
// Reads hnew, computes logits/argmax/log_softmax/topi (+h_final at t=511).
// ---------------------------------------------------------------------------
__global__ __launch_bounds__(512)
void logits_out(const float* __restrict__ hnew,
                const float* __restrict__ W_out, const float* __restrict__ b_out,
                int* __restrict__ topi_out, float* __restrict__ lp,
                float* __restrict__ hfin, int t) {
    const int b = blockIdx.x;
    const int tid = threadIdx.x;
    __shared__ __align__(16) float sh[Hdim];
    __shared__ float sl[16];

    const int j0 = tid * 4;
    f4 o0 = *(const f4*)(hnew + (size_t)b * Hdim + j0);
    *(f4*)(sh + j0) = o0;
    __syncthreads();

    const int w = tid >> 6, l = tid & 63;
    for (int o = w; o < Odim; o += 8) {
        const float* wo = W_out + (size_t)o * Hdim;
        float s = 0.f;
        #pragma unroll
        for (int i = 0; i < 32; ++i)
            s = fmaf(sh[l + 64 * i], wo[l + 64 * i], s);
        #pragma unroll
        for (int off = 32; off >= 1; off >>= 1)
            s += __shfl_down(s, off);
        if (l == 0) sl[o] = s + b_out[o];
    }
    __syncthreads();
    if (tid == 0) {
        float m = sl[0]; int bi = 0;
        #pragma unroll
        for (int o = 1; o < Odim; ++o)
            if (sl[o] > m) { m = sl[o]; bi = o; }   // strict > = first max
        float ssum = 0.f;
        #pragma unroll
        for (int o = 0; o < Odim; ++o) ssum += expf(sl[o] - m);
        topi_out[b] = bi;
        sl[14] = m + logf(ssum);
    }
    __syncthreads();
    if (tid < Odim)
        lp[(size_t)b * (Tdim * Odim) + (size_t)t * Odim + tid] = sl[tid] - sl[14];
    if (hfin)
        *(f4*)(hfin + (size_t)b * Hdim + j0) = o0;
}

// ---------------------------------------------------------------------------
extern "C" void kernel_launch(void* const* d_in, const int* in_sizes, int n_in,
                              void* d_out, int out_size, void* d_ws, size_t ws_size,
                              hipStream_t stream) {
    const float* enc_hidden = (const float*)d_in[1];
    const float* target     = (const float*)d_in[2];
    const float* W_ih       = (const float*)d_in[3];
    const float* W_hh       = (const float*)d_in[4];
    const float* b_ih       = (const float*)d_in[5];
    const float* b_hh       = (const float*)d_in[6];
    const float* W_out      = (const float*)d_in[7];
    const float* b_out      = (const float*)d_in[8];

    float* out  = (float*)d_out;
    float* lp   = out;
    float* hfin = out + (size_t)Bdim * Tdim * Odim;

    float* ws    = (float*)d_ws;
    float* hb0   = ws;                        // 524288 f
    float* hb1   = hb0 + 524288;              // 524288 f
    float* Gt    = hb1 + 524288;              // 92160 f
    float* gi0   = Gt + 15 * G3;              // 1572864 f
    float* apad  = gi0 + (size_t)Bdim * G3;
    _Float16* A0h = (_Float16*)apad;                            // 524288 h
    _Float16* A0l = A0h + (size_t)Bdim * Hdim;                  // 524288 h
    _Float16* A1h = A0l + (size_t)Bdim * Hdim;                  // 524288 h
    _Float16* A1l = A1h + (size_t)Bdim * Hdim;                  // 524288 h
    _Float16* Bh = (_Float16*)(apad + 4 * (size_t)Bdim * G3);   // 12582912 h
    _Float16* Bl = Bh + (size_t)G3 * Hdim;                      // 12582912 h
    int* topibuf = (int*)(Bl + (size_t)G3 * Hdim);              // 512 ints

    prep_gtable<<<(15 * G3 + 255) / 256, 256, 0, stream>>>(b_ih, W_ih, Gt);
    prep_gi0<<<(Bdim * G3) / 256, 256, 0, stream>>>(b_ih, W_ih, target, gi0);
    prep_Bpack<<<(G3 * 256) / 256, 256, 0, stream>>>(W_hh, Bh, Bl);
    prep_A0<<<(Bdim * 256) / 256, 256, 0, stream>>>(enc_hidden, A0h, A0l);

    for (int t = 0; t < Tdim; ++t) {
        float* hnew = (t & 1) ? hb1 : hb0;
        const float* hprev = (t == 0) ? enc_hidden : ((t & 1) ? hb0 : hb1);
        const _Float16* Aih = (t & 1) ? A1h : A0h;
        const _Float16* Ail = (t & 1) ? A1l : A0l;
        _Float16* Aoh = (t & 1) ? A0h : A1h;
        _Float16* Aol = (t & 1) ? A0l : A1l;
        int* tin  = topibuf + ((t + 1) & 1) * 256;
        int* tout = topibuf + (t & 1) * 256;
        gru_step<<<256, 512, 0, stream>>>(Aih, Ail, Bh, Bl, hprev, hnew,
                                          Gt, gi0, b_hh, tin, Aoh, Aol, t);
        logits_out<<<256, 512, 0, stream>>>(hnew, W_out, b_out, tout, lp,
                                            (t == Tdim - 1) ? hfin : nullptr, t);
    }
}